// Round 1
// baseline (106.390 us; speedup 1.0000x reference)
//
#include <hip/hip_runtime.h>
#include <hip/hip_bf16.h>
#include <stdint.h>

// ---- problem constants ----
#define S_LEN   2048
#define HIDDEN  768
#define NHEADS  12
#define HDIM    64
#define KSEL    64
#define QKV_LD  2304   // fused q|k|v row stride (floats)

typedef __attribute__((ext_vector_type(8))) short short8;
typedef __attribute__((ext_vector_type(4))) float f32x4;

typedef const __attribute__((address_space(1))) void* gas_ptr;
typedef __attribute__((address_space(3))) void* las_ptr;

__device__ __forceinline__ short f2b(float f) {
    union { float f; uint32_t u; } v; v.f = f;
    uint32_t u = v.u;
    uint32_t r = (u + 0x7FFFu + ((u >> 16) & 1u)) >> 16;
    return (short)r;
}

// ---------------- f32 -> bf16 convert (RNE), n divisible by 1024 ----------------
__global__ __launch_bounds__(256) void f2b_kernel(const float* __restrict__ in,
                                                  short* __restrict__ out, int n) {
    int i = (blockIdx.x * 256 + threadIdx.x) * 4;
    if (i >= n) return;
    float4 v = *(const float4*)(in + i);
    short4 o = make_short4(f2b(v.x), f2b(v.y), f2b(v.z), f2b(v.w));
    *(short4*)(out + i) = o;
}

// ---------------- bf16 GEMM: C[m][n] = sum_k A[m][k] * B[n][k] ----------------
// A: (M x K) bf16 row-major, B: (N x K) bf16 row-major (i.e. B^T input), C f32.
// Tile 128x128, BK=64, 4 waves, mfma_f32_16x16x32_bf16, XOR-swizzled LDS.
__global__ __launch_bounds__(256)
void gemm_bt(const short* __restrict__ A, const short* __restrict__ B,
             float* __restrict__ C, int K, int ntn, int ldc) {
    __shared__ short sA[128 * 64];
    __shared__ short sB[128 * 64];

    const int bm = blockIdx.x / ntn;
    const int bn = blockIdx.x % ntn;
    const int tid = threadIdx.x;
    const int lane = tid & 63;
    const int w = tid >> 6;        // wave 0..3
    const int wr = w >> 1;         // wave row 0..1
    const int wc = w & 1;          // wave col 0..1

    f32x4 acc[4][4] = {};

    // staging geometry (per wave): 4 calls x 64 lanes x 16B = 4KB = 32 rows of 128B
    const int st_r_base = w * 32 + (lane >> 3);  // + c*8
    const int st_cb = (lane & 7) * 16;           // byte col within 128B row

    for (int k0 = 0; k0 < K; k0 += 64) {
        __syncthreads();   // protect previous iteration's reads
        // stage A
        for (int c = 0; c < 4; ++c) {
            int r = st_r_base + c * 8;
            int scb = st_cb ^ ((r & 7) << 4);   // pre-swizzled global source
            const char* gp = (const char*)(A + (size_t)(bm * 128 + r) * K + k0) + scb;
            las_ptr lp = (las_ptr)((char*)sA + w * 4096 + c * 1024);
            __builtin_amdgcn_global_load_lds((gas_ptr)gp, lp, 16, 0, 0);
        }
        // stage B
        for (int c = 0; c < 4; ++c) {
            int r = st_r_base + c * 8;
            int scb = st_cb ^ ((r & 7) << 4);
            const char* gp = (const char*)(B + (size_t)(bn * 128 + r) * K + k0) + scb;
            las_ptr lp = (las_ptr)((char*)sB + w * 4096 + c * 1024);
            __builtin_amdgcn_global_load_lds((gas_ptr)gp, lp, 16, 0, 0);
        }
        __syncthreads();   // loads drained (compiler emits vmcnt(0) before barrier)

        #pragma unroll
        for (int kh = 0; kh < 2; ++kh) {
            const int kb = kh * 64 + ((lane >> 4) << 4);
            short8 av[4], bv[4];
            #pragma unroll
            for (int mi = 0; mi < 4; ++mi) {
                int row = wr * 64 + mi * 16 + (lane & 15);
                av[mi] = *(const short8*)((const char*)sA + row * 128 + (kb ^ ((row & 7) << 4)));
            }
            #pragma unroll
            for (int ni = 0; ni < 4; ++ni) {
                int row = wc * 64 + ni * 16 + (lane & 15);
                bv[ni] = *(const short8*)((const char*)sB + row * 128 + (kb ^ ((row & 7) << 4)));
            }
            #pragma unroll
            for (int mi = 0; mi < 4; ++mi)
                #pragma unroll
                for (int ni = 0; ni < 4; ++ni)
                    acc[mi][ni] = __builtin_amdgcn_mfma_f32_16x16x32_bf16(
                        av[mi], bv[ni], acc[mi][ni], 0, 0, 0);
        }
    }

    // epilogue: D row=(lane>>4)*4+r, col=lane&15 (verified layout)
    const int crow0 = bm * 128 + wr * 64;
    const int ccol0 = bn * 128 + wc * 64;
    #pragma unroll
    for (int mi = 0; mi < 4; ++mi)
        #pragma unroll
        for (int ni = 0; ni < 4; ++ni)
            #pragma unroll
            for (int r = 0; r < 4; ++r) {
                int grow = crow0 + mi * 16 + ((lane >> 4) << 2) + r;
                int gcol = ccol0 + ni * 16 + (lane & 15);
                C[(size_t)grow * ldc + gcol] = acc[mi][ni][r];
            }
}

// ---------------- sliding-window attention ----------------
// QKV: [S][2304] f32 (q|k|v). Out: [S][768] bf16.
// Block = 4 waves = 4 consecutive queries of one head. Window <= 64, union <= 67 rows.
__global__ __launch_bounds__(256)
void attn_kernel(const float* __restrict__ QKV, short* __restrict__ O) {
    __shared__ float Kl[67 * 65];
    __shared__ float Vl[67 * 65];
    __shared__ float ql[4 * 64];

    const int h = blockIdx.x / 512;       // head
    const int s0 = (blockIdx.x % 512) * 4;
    const int w0min = (s0 - 63 > 0) ? (s0 - 63) : 0;
    const int nrows = s0 + 3 - w0min + 1;

    // stage K/V window union (coalesced: consecutive threads -> consecutive d)
    const int total = nrows * 64;
    for (int idx = threadIdx.x; idx < total; idx += 256) {
        int r = idx >> 6, d = idx & 63;
        const float* src = QKV + (size_t)(w0min + r) * QKV_LD + h * 64 + d;
        Kl[r * 65 + d] = src[768];
        Vl[r * 65 + d] = src[1536];
    }
    const int w = threadIdx.x >> 6, lane = threadIdx.x & 63;
    const int s = s0 + w;
    ql[w * 64 + lane] = QKV[(size_t)s * QKV_LD + h * 64 + lane];
    __syncthreads();

    const int w0 = (s - 63 > 0) ? (s - 63) : 0;
    const int nv = s - w0 + 1;            // valid window entries (wave-uniform)
    const int base = w0 - w0min;

    // lane = window slot j
    float sc = -1e30f;
    if (lane < nv) {
        const float* kr = &Kl[(base + lane) * 65];
        const float* qq = &ql[w * 64];
        float a = 0.f;
        #pragma unroll
        for (int d = 0; d < 64; ++d) a += qq[d] * kr[d];
        sc = a * 0.125f;
    }
    float m = sc;
    #pragma unroll
    for (int off = 32; off; off >>= 1) m = fmaxf(m, __shfl_xor(m, off));
    float e = (lane < nv) ? __expf(sc - m) : 0.f;
    float ssum = e;
    #pragma unroll
    for (int off = 32; off; off >>= 1) ssum += __shfl_xor(ssum, off);
    const float wgt = e / ssum;

    // lane = dim d
    float o = 0.f;
    for (int j = 0; j < nv; ++j) {
        float wj = __shfl(wgt, j);
        o += wj * Vl[(base + j) * 65 + lane];
    }
    O[(size_t)s * HIDDEN + h * 64 + lane] = f2b(o);
}

// ---------------- launcher ----------------
extern "C" void kernel_launch(void* const* d_in, const int* in_sizes, int n_in,
                              void* d_out, int out_size, void* d_ws, size_t ws_size,
                              hipStream_t stream) {
    const float* X  = (const float*)d_in[0];
    const float* Wq = (const float*)d_in[1];
    const float* Wk = (const float*)d_in[2];
    const float* Wv = (const float*)d_in[3];
    const float* Wo = (const float*)d_in[4];
    float* out = (float*)d_out;

    char* ws = (char*)d_ws;
    short* Xb    = (short*)(ws);                 // 2048*768 bf16      (3,145,728 B)
    short* Wqkvb = (short*)(ws + 3145728);       // 2304*768 bf16      (3,538,944 B)
    short* Wob   = (short*)(ws + 6684672);       // 768*768 bf16       (1,179,648 B)
    float* QKV   = (float*)(ws + 7864320);       // 2048*2304 f32      (18,874,368 B)
    short* Attnb = (short*)(ws + 26738688);      // 2048*768 bf16      (3,145,728 B)

    const int NX = S_LEN * HIDDEN;       // 1,572,864
    const int NW = HIDDEN * HIDDEN;      // 589,824

    f2b_kernel<<<NX / 1024, 256, 0, stream>>>(X, Xb, NX);
    f2b_kernel<<<NW / 1024, 256, 0, stream>>>(Wq, Wqkvb, NW);
    f2b_kernel<<<NW / 1024, 256, 0, stream>>>(Wk, Wqkvb + NW, NW);
    f2b_kernel<<<NW / 1024, 256, 0, stream>>>(Wv, Wqkvb + 2 * NW, NW);
    f2b_kernel<<<NW / 1024, 256, 0, stream>>>(Wo, Wob, NW);

    // QKV = X @ [Wq;Wk;Wv]^T : M=2048, N=2304, K=768
    gemm_bt<<<(S_LEN / 128) * (QKV_LD / 128), 256, 0, stream>>>(Xb, Wqkvb, QKV, HIDDEN, QKV_LD / 128, QKV_LD);

    // sliding-window attention
    attn_kernel<<<NHEADS * (S_LEN / 4), 256, 0, stream>>>(QKV, Attnb);

    // out = attn @ Wo^T : M=2048, N=768, K=768
    gemm_bt<<<(S_LEN / 128) * (HIDDEN / 128), 256, 0, stream>>>(Attnb, Wob, out, HIDDEN, HIDDEN / 128, HIDDEN);
}

// Round 2
// 58.543 us; speedup vs baseline: 1.8173x; 1.8173x over previous
//
#include <hip/hip_runtime.h>
#include <hip/hip_bf16.h>
#include <stdint.h>

// ---- problem constants ----
#define S_LEN   2048
#define HIDDEN  768
#define NHEADS  12
#define QKV_LD  2304   // fused q|k|v row stride (elements)
#define NW      589824 // 768*768

typedef __attribute__((ext_vector_type(8))) short short8;
typedef __attribute__((ext_vector_type(4))) float f32x4;

typedef const __attribute__((address_space(1))) void* gas_ptr;
typedef __attribute__((address_space(3))) void* las_ptr;

__device__ __forceinline__ short f2b(float f) {
    union { float f; uint32_t u; } v; v.f = f;
    uint32_t u = v.u;
    uint32_t r = (u + 0x7FFFu + ((u >> 16) & 1u)) >> 16;
    return (short)r;
}

// ---------------- f32 -> bf16 convert (RNE) ----------------
__global__ __launch_bounds__(256) void f2b_kernel(const float* __restrict__ in,
                                                  short* __restrict__ out, int n) {
    int i = (blockIdx.x * 256 + threadIdx.x) * 4;
    if (i >= n) return;
    float4 v = *(const float4*)(in + i);
    *(short4*)(out + i) = make_short4(f2b(v.x), f2b(v.y), f2b(v.z), f2b(v.w));
}

// convert all 4 weight matrices in one launch (grid = 4*576)
__global__ __launch_bounds__(256)
void f2b4_kernel(const float* __restrict__ s0, const float* __restrict__ s1,
                 const float* __restrict__ s2, const float* __restrict__ s3,
                 short* __restrict__ dqkv, short* __restrict__ dwo) {
    int wb = blockIdx.x / 576;
    int lb = blockIdx.x % 576;
    int i = lb * 1024 + threadIdx.x * 4;
    const float* src = wb == 0 ? s0 : wb == 1 ? s1 : wb == 2 ? s2 : s3;
    short* dst = wb < 3 ? dqkv + wb * NW : dwo;
    float4 v = *(const float4*)(src + i);
    *(short4*)(dst + i) = make_short4(f2b(v.x), f2b(v.y), f2b(v.z), f2b(v.w));
}

// ---------------- bf16 GEMM: C[m][n] = sum_k A[m][k] * B[n][k] ----------------
// 128x128 tile, BK=64, 4 waves, mfma_f32_16x16x32_bf16, XOR-swizzled LDS.
// OUT_BF16: store bf16 (for QKV), else f32.
template<int OUT_BF16>
__global__ __launch_bounds__(256)
void gemm_bt(const short* __restrict__ A, const short* __restrict__ B,
             void* __restrict__ Cv, int K, int ntn, int ldc) {
    __shared__ short sA[128 * 64];
    __shared__ short sB[128 * 64];

    const int bm = blockIdx.x / ntn;
    const int bn = blockIdx.x % ntn;
    const int tid = threadIdx.x;
    const int lane = tid & 63;
    const int w = tid >> 6;
    const int wr = w >> 1;
    const int wc = w & 1;

    f32x4 acc[4][4] = {};

    const int st_r_base = w * 32 + (lane >> 3);
    const int st_cb = (lane & 7) * 16;

    for (int k0 = 0; k0 < K; k0 += 64) {
        __syncthreads();
        for (int c = 0; c < 4; ++c) {
            int r = st_r_base + c * 8;
            int scb = st_cb ^ ((r & 7) << 4);
            const char* gp = (const char*)(A + (size_t)(bm * 128 + r) * K + k0) + scb;
            las_ptr lp = (las_ptr)((char*)sA + w * 4096 + c * 1024);
            __builtin_amdgcn_global_load_lds((gas_ptr)gp, lp, 16, 0, 0);
        }
        for (int c = 0; c < 4; ++c) {
            int r = st_r_base + c * 8;
            int scb = st_cb ^ ((r & 7) << 4);
            const char* gp = (const char*)(B + (size_t)(bn * 128 + r) * K + k0) + scb;
            las_ptr lp = (las_ptr)((char*)sB + w * 4096 + c * 1024);
            __builtin_amdgcn_global_load_lds((gas_ptr)gp, lp, 16, 0, 0);
        }
        __syncthreads();

        #pragma unroll
        for (int kh = 0; kh < 2; ++kh) {
            const int kb = kh * 64 + ((lane >> 4) << 4);
            short8 av[4], bv[4];
            #pragma unroll
            for (int mi = 0; mi < 4; ++mi) {
                int row = wr * 64 + mi * 16 + (lane & 15);
                av[mi] = *(const short8*)((const char*)sA + row * 128 + (kb ^ ((row & 7) << 4)));
            }
            #pragma unroll
            for (int ni = 0; ni < 4; ++ni) {
                int row = wc * 64 + ni * 16 + (lane & 15);
                bv[ni] = *(const short8*)((const char*)sB + row * 128 + (kb ^ ((row & 7) << 4)));
            }
            #pragma unroll
            for (int mi = 0; mi < 4; ++mi)
                #pragma unroll
                for (int ni = 0; ni < 4; ++ni)
                    acc[mi][ni] = __builtin_amdgcn_mfma_f32_16x16x32_bf16(
                        av[mi], bv[ni], acc[mi][ni], 0, 0, 0);
        }
    }

    const int crow0 = bm * 128 + wr * 64;
    const int ccol0 = bn * 128 + wc * 64;
    #pragma unroll
    for (int mi = 0; mi < 4; ++mi)
        #pragma unroll
        for (int ni = 0; ni < 4; ++ni)
            #pragma unroll
            for (int r = 0; r < 4; ++r) {
                int grow = crow0 + mi * 16 + ((lane >> 4) << 2) + r;
                int gcol = ccol0 + ni * 16 + (lane & 15);
                if (OUT_BF16)
                    ((short*)Cv)[(size_t)grow * ldc + gcol] = f2b(acc[mi][ni][r]);
                else
                    ((float*)Cv)[(size_t)grow * ldc + gcol] = acc[mi][ni][r];
            }
}

// ---------------- MFMA sliding-window attention ----------------
// QKV: [S][2304] bf16. O: [S][768] bf16.
// Block = (head, 64-query tile). Keys/values staged for rows [s0-64, s0+63].
// 4 waves, wave w owns queries w*16..w*16+15.
__global__ __launch_bounds__(256)
void attn_mfma(const short* __restrict__ QKV, short* __restrict__ O) {
    __shared__ short sQ[64 * 64];        // [q][d]   swz, 8KB
    __shared__ short sK[128 * 64];       // [kt][d]  swz, 16KB
    __shared__ short sVt[64 * 128];      // [d][kt]  swz, 16KB
    __shared__ short sP[4][16 * 128];    // per-wave [q][kt] swz, 16KB

    const int h = blockIdx.x % NHEADS;
    const int s0 = (blockIdx.x / NHEADS) * 64;
    const int tid = threadIdx.x, lane = tid & 63, w = tid >> 6;

    // ---- stage Q via global_load_lds (pre-swizzled source) ----
    #pragma unroll
    for (int c = 0; c < 2; ++c) {
        int r = (w * 2 + c) * 8 + (lane >> 3);
        int scb = ((lane & 7) * 16) ^ ((r & 7) << 4);
        const char* gp = (const char*)(QKV + (size_t)(s0 + r) * QKV_LD + h * 64) + scb;
        las_ptr lp = (las_ptr)((char*)sQ + (w * 2 + c) * 1024);
        __builtin_amdgcn_global_load_lds((gas_ptr)gp, lp, 16, 0, 0);
    }
    // ---- stage K rows s0-64+r (clamped; masked later) ----
    #pragma unroll
    for (int c = 0; c < 4; ++c) {
        int r = (w * 4 + c) * 8 + (lane >> 3);
        int gr = s0 - 64 + r; if (gr < 0) gr = 0;
        int scb = ((lane & 7) * 16) ^ ((r & 7) << 4);
        const char* gp = (const char*)(QKV + (size_t)gr * QKV_LD + 768 + h * 64) + scb;
        las_ptr lp = (las_ptr)((char*)sK + (w * 4 + c) * 1024);
        __builtin_amdgcn_global_load_lds((gas_ptr)gp, lp, 16, 0, 0);
    }
    // ---- stage V transposed into sVt[d][key] (reg transpose, rotated writes) ----
    #pragma unroll
    for (int it = 0; it < 4; ++it) {
        int id = it * 256 + tid;
        int key = id >> 3;
        int d0 = (id & 7) * 8;
        int gr = s0 - 64 + key; if (gr < 0) gr = 0;
        short8 v = *(const short8*)(QKV + (size_t)gr * QKV_LD + 1536 + h * 64 + d0);
        #pragma unroll
        for (int j = 0; j < 8; ++j) {
            int jj = (j + tid) & 7;           // rotate to avoid same-bank writes
            int row = d0 + jj;
            int b = row * 256 + ((key * 2) ^ ((row & 7) << 4));
            *(short*)((char*)sVt + b) = v[jj];
        }
    }
    __syncthreads();

    // ---- QK^T: S[q][kt], 8 key tiles ----
    const int qrow = w * 16 + (lane & 15);
    short8 qf[2];
    #pragma unroll
    for (int kk = 0; kk < 2; ++kk) {
        int cb = kk * 64 + ((lane >> 4) << 4);
        qf[kk] = *(const short8*)((const char*)sQ + qrow * 128 + (cb ^ ((qrow & 7) << 4)));
    }
    f32x4 s_acc[8];
    #pragma unroll
    for (int ct = 0; ct < 8; ++ct) {
        s_acc[ct] = (f32x4){0.f, 0.f, 0.f, 0.f};
        int krow = ct * 16 + (lane & 15);
        #pragma unroll
        for (int kk = 0; kk < 2; ++kk) {
            int cb = kk * 64 + ((lane >> 4) << 4);
            short8 kf = *(const short8*)((const char*)sK + krow * 128 + (cb ^ ((krow & 7) << 4)));
            s_acc[ct] = __builtin_amdgcn_mfma_f32_16x16x32_bf16(qf[kk], kf, s_acc[ct], 0, 0, 0);
        }
    }

    // ---- band mask + softmax (per query row, spread over 16 lanes x 8 tiles) ----
    const int kcol = lane & 15;
    const int qb = w * 16 + ((lane >> 4) << 2);   // + r = query within 64-block
    float p[8][4];
    #pragma unroll
    for (int r = 0; r < 4; ++r) {
        int q = qb + r;
        float m = -1e30f;
        #pragma unroll
        for (int ct = 0; ct < 8; ++ct) {
            int kt = ct * 16 + kcol;
            bool valid = (kt > q) && (kt <= q + 64) && (s0 + kt >= 64);
            float sc = valid ? s_acc[ct][r] * 0.125f : -1e30f;
            p[ct][r] = sc;
            m = fmaxf(m, sc);
        }
        #pragma unroll
        for (int off = 1; off < 16; off <<= 1) m = fmaxf(m, __shfl_xor(m, off));
        float sm = 0.f;
        #pragma unroll
        for (int ct = 0; ct < 8; ++ct) {
            float e = __expf(p[ct][r] - m);
            p[ct][r] = e;
            sm += e;
        }
        #pragma unroll
        for (int off = 1; off < 16; off <<= 1) sm += __shfl_xor(sm, off);
        float inv = 1.f / sm;
        #pragma unroll
        for (int ct = 0; ct < 8; ++ct) p[ct][r] *= inv;
    }

    // ---- write P to per-wave swizzled LDS [16][128] ----
    #pragma unroll
    for (int ct = 0; ct < 8; ++ct)
        #pragma unroll
        for (int r = 0; r < 4; ++r) {
            int row = ((lane >> 4) << 2) + r;
            int b = row * 256 + (((ct * 16 + kcol) * 2) ^ ((row & 7) << 4));
            *(short*)((char*)&sP[w][0] + b) = f2b(p[ct][r]);
        }

    // ---- PV: O[q][d] = P(16x128) . V(128x64) ----
    short8 pf[4];
    #pragma unroll
    for (int kk = 0; kk < 4; ++kk) {
        int row = lane & 15;
        int cb = kk * 64 + ((lane >> 4) << 4);
        pf[kk] = *(const short8*)((const char*)&sP[w][0] + row * 256 + (cb ^ ((row & 7) << 4)));
    }
    f32x4 o_acc[4];
    #pragma unroll
    for (int nt = 0; nt < 4; ++nt) {
        o_acc[nt] = (f32x4){0.f, 0.f, 0.f, 0.f};
        #pragma unroll
        for (int kk = 0; kk < 4; ++kk) {
            int vrow = nt * 16 + (lane & 15);
            int cb = kk * 64 + ((lane >> 4) << 4);
            short8 vf = *(const short8*)((const char*)sVt + vrow * 256 + (cb ^ ((vrow & 7) << 4)));
            o_acc[nt] = __builtin_amdgcn_mfma_f32_16x16x32_bf16(pf[kk], vf, o_acc[nt], 0, 0, 0);
        }
    }

    // ---- store O (bf16) ----
    #pragma unroll
    for (int nt = 0; nt < 4; ++nt)
        #pragma unroll
        for (int r = 0; r < 4; ++r) {
            int q = s0 + qb + r;
            int dcol = h * 64 + nt * 16 + (lane & 15);
            O[(size_t)q * HIDDEN + dcol] = f2b(o_acc[nt][r]);
        }
}

// ---------------- launcher ----------------
extern "C" void kernel_launch(void* const* d_in, const int* in_sizes, int n_in,
                              void* d_out, int out_size, void* d_ws, size_t ws_size,
                              hipStream_t stream) {
    const float* X  = (const float*)d_in[0];
    const float* Wq = (const float*)d_in[1];
    const float* Wk = (const float*)d_in[2];
    const float* Wv = (const float*)d_in[3];
    const float* Wo = (const float*)d_in[4];
    float* out = (float*)d_out;

    char* ws = (char*)d_ws;
    short* Xb    = (short*)(ws);                 // 2048*768   bf16
    short* Wqkvb = (short*)(ws + 3145728);       // 2304*768   bf16
    short* Wob   = (short*)(ws + 6684672);       // 768*768    bf16
    short* QKVb  = (short*)(ws + 7864320);       // 2048*2304  bf16
    short* Attnb = (short*)(ws + 17301504);      // 2048*768   bf16

    const int NX = S_LEN * HIDDEN;

    f2b_kernel<<<NX / 1024, 256, 0, stream>>>(X, Xb, NX);
    f2b4_kernel<<<4 * (NW / 1024), 256, 0, stream>>>(Wq, Wk, Wv, Wo, Wqkvb, Wob);

    // QKV = X @ [Wq;Wk;Wv]^T : M=2048, N=2304, K=768 -> bf16
    gemm_bt<1><<<(S_LEN / 128) * (QKV_LD / 128), 256, 0, stream>>>(Xb, Wqkvb, QKVb, HIDDEN, QKV_LD / 128, QKV_LD);

    // sliding-window attention (MFMA)
    attn_mfma<<<(S_LEN / 64) * NHEADS, 256, 0, stream>>>(QKVb, Attnb);

    // out = attn @ Wo^T : M=2048, N=768, K=768 -> f32
    gemm_bt<0><<<(S_LEN / 128) * (HIDDEN / 128), 256, 0, stream>>>(Attnb, Wob, out, HIDDEN, HIDDEN / 128, HIDDEN);
}

// Round 3
// 57.114 us; speedup vs baseline: 1.8628x; 1.0250x over previous
//
#include <hip/hip_runtime.h>
#include <hip/hip_bf16.h>
#include <stdint.h>

// ---- problem constants ----
#define S_LEN   2048
#define HIDDEN  768
#define NHEADS  12
#define QKV_LD  2304   // fused q|k|v row stride (elements)
#define NW      589824 // 768*768

typedef __attribute__((ext_vector_type(8))) short short8;
typedef __attribute__((ext_vector_type(4))) float f32x4;

typedef const __attribute__((address_space(1))) void* gas_ptr;
typedef __attribute__((address_space(3))) void* las_ptr;

__device__ __forceinline__ short f2b(float f) {
    union { float f; uint32_t u; } v; v.f = f;
    uint32_t u = v.u;
    uint32_t r = (u + 0x7FFFu + ((u >> 16) & 1u)) >> 16;
    return (short)r;
}

// ---------------- all f32 -> bf16 converts in one launch ----------------
// blocks [0,1536): X (2048x768). blocks [1536, 1536+4*576): Wq,Wk,Wv,Wo.
__global__ __launch_bounds__(256)
void convert_all(const float* __restrict__ X,
                 const float* __restrict__ Wq, const float* __restrict__ Wk,
                 const float* __restrict__ Wv, const float* __restrict__ Wo,
                 short* __restrict__ Xb, short* __restrict__ Wqkvb,
                 short* __restrict__ Wob) {
    int b = blockIdx.x;
    const float* src;
    short* dst;
    int i;
    if (b < 1536) {
        src = X; dst = Xb; i = b * 1024 + threadIdx.x * 4;
    } else {
        int wb = (b - 1536) / 576, lb = (b - 1536) % 576;
        src = wb == 0 ? Wq : wb == 1 ? Wk : wb == 2 ? Wv : Wo;
        dst = wb < 3 ? Wqkvb + wb * NW : Wob;
        i = lb * 1024 + threadIdx.x * 4;
    }
    float4 v = *(const float4*)(src + i);
    *(short4*)(dst + i) = make_short4(f2b(v.x), f2b(v.y), f2b(v.z), f2b(v.w));
}

// ---------------- bf16 GEMM: C[m][n] = sum_k A[m][k] * B[n][k] ----------------
// 128x128 tile, BK=64, 4 waves, mfma_f32_16x16x32_bf16, XOR-swizzled LDS,
// 2-phase double-buffered K-loop (stage next tile overlapped with compute).
template<int OUT_BF16>
__global__ __launch_bounds__(256)
void gemm_bt(const short* __restrict__ A, const short* __restrict__ B,
             void* __restrict__ Cv, int K, int ntn, int ldc) {
    __shared__ short sA[2][128 * 64];
    __shared__ short sB[2][128 * 64];

    const int bm = blockIdx.x / ntn;
    const int bn = blockIdx.x % ntn;
    const int tid = threadIdx.x;
    const int lane = tid & 63;
    const int w = tid >> 6;
    const int wr = w >> 1;
    const int wc = w & 1;

    f32x4 acc[4][4] = {};

    const int st_r_base = w * 32 + (lane >> 3);
    const int st_cb = (lane & 7) * 16;

    auto stage = [&](int buf, int k0) {
        #pragma unroll
        for (int c = 0; c < 4; ++c) {
            int r = st_r_base + c * 8;
            int scb = st_cb ^ ((r & 7) << 4);
            const char* gpA = (const char*)(A + (size_t)(bm * 128 + r) * K + k0) + scb;
            __builtin_amdgcn_global_load_lds((gas_ptr)gpA,
                (las_ptr)((char*)&sA[buf][0] + w * 4096 + c * 1024), 16, 0, 0);
            const char* gpB = (const char*)(B + (size_t)(bn * 128 + r) * K + k0) + scb;
            __builtin_amdgcn_global_load_lds((gas_ptr)gpB,
                (las_ptr)((char*)&sB[buf][0] + w * 4096 + c * 1024), 16, 0, 0);
        }
    };

    const int NT = K >> 6;
    stage(0, 0);
    __syncthreads();                 // vmcnt(0) drain + barrier: buf0 ready
    int cur = 0;
    for (int t = 0; t < NT; ++t) {
        if (t + 1 < NT) stage(cur ^ 1, (t + 1) * 64);   // prefetch next tile

        #pragma unroll
        for (int kh = 0; kh < 2; ++kh) {
            const int kb = kh * 64 + ((lane >> 4) << 4);
            short8 av[4], bv[4];
            #pragma unroll
            for (int mi = 0; mi < 4; ++mi) {
                int row = wr * 64 + mi * 16 + (lane & 15);
                av[mi] = *(const short8*)((const char*)&sA[cur][0] + row * 128 + (kb ^ ((row & 7) << 4)));
            }
            #pragma unroll
            for (int ni = 0; ni < 4; ++ni) {
                int row = wc * 64 + ni * 16 + (lane & 15);
                bv[ni] = *(const short8*)((const char*)&sB[cur][0] + row * 128 + (kb ^ ((row & 7) << 4)));
            }
            #pragma unroll
            for (int mi = 0; mi < 4; ++mi)
                #pragma unroll
                for (int ni = 0; ni < 4; ++ni)
                    acc[mi][ni] = __builtin_amdgcn_mfma_f32_16x16x32_bf16(
                        av[mi], bv[ni], acc[mi][ni], 0, 0, 0);
        }
        __syncthreads();             // prefetch landed + all reads of buf[cur] done
        cur ^= 1;
    }

    const int crow0 = bm * 128 + wr * 64;
    const int ccol0 = bn * 128 + wc * 64;
    #pragma unroll
    for (int mi = 0; mi < 4; ++mi)
        #pragma unroll
        for (int ni = 0; ni < 4; ++ni)
            #pragma unroll
            for (int r = 0; r < 4; ++r) {
                int grow = crow0 + mi * 16 + ((lane >> 4) << 2) + r;
                int gcol = ccol0 + ni * 16 + (lane & 15);
                if (OUT_BF16)
                    ((short*)Cv)[(size_t)grow * ldc + gcol] = f2b(acc[mi][ni][r]);
                else
                    ((float*)Cv)[(size_t)grow * ldc + gcol] = acc[mi][ni][r];
            }
}

// ---------------- MFMA sliding-window attention ----------------
// QKV: [S][2304] bf16. O: [S][768] bf16.
// Block = (head, 64-query tile). K/V staged for rows [s0-64, s0+63].
__global__ __launch_bounds__(256)
void attn_mfma(const short* __restrict__ QKV, short* __restrict__ O) {
    __shared__ short sK[128 * 64];       // [kt][d]  swz, 16KB
    __shared__ short sVt[64 * 128];      // [d][kt]  swz, 16KB
    __shared__ short sP[4][16 * 128];    // per-wave [q][kt] swz, 16KB

    const int h = blockIdx.x % NHEADS;
    const int s0 = (blockIdx.x / NHEADS) * 64;
    const int tid = threadIdx.x, lane = tid & 63, w = tid >> 6;

    // ---- stage K rows s0-64+r (clamped; masked later) via global_load_lds ----
    #pragma unroll
    for (int c = 0; c < 4; ++c) {
        int r = (w * 4 + c) * 8 + (lane >> 3);
        int gr = s0 - 64 + r; if (gr < 0) gr = 0;
        int scb = ((lane & 7) * 16) ^ ((r & 7) << 4);
        const char* gp = (const char*)(QKV + (size_t)gr * QKV_LD + 768 + h * 64) + scb;
        __builtin_amdgcn_global_load_lds((gas_ptr)gp,
            (las_ptr)((char*)sK + (w * 4 + c) * 1024), 16, 0, 0);
    }
    // ---- stage V transposed: thread = (4 keys, 8 dims) -> 8x ds_write_b64 ----
    {
        const int d0 = (tid & 7) * 8;
        const int kbase = (tid >> 3) * 4;
        short8 v[4];
        #pragma unroll
        for (int i = 0; i < 4; ++i) {
            int gr = s0 - 64 + kbase + i; if (gr < 0) gr = 0;
            v[i] = *(const short8*)(QKV + (size_t)gr * QKV_LD + 1536 + h * 64 + d0);
        }
        #pragma unroll
        for (int j = 0; j < 8; ++j) {
            int row = d0 + j;
            int b = row * 256 + ((kbase * 2) ^ ((row & 7) << 4));
            *(short4*)((char*)sVt + b) = make_short4(v[0][j], v[1][j], v[2][j], v[3][j]);
        }
    }
    // ---- Q fragments directly from global (no LDS round-trip) ----
    const int qrow = w * 16 + (lane & 15);
    short8 qf[2];
    #pragma unroll
    for (int kk = 0; kk < 2; ++kk)
        qf[kk] = *(const short8*)(QKV + (size_t)(s0 + qrow) * QKV_LD + h * 64
                                  + kk * 32 + ((lane >> 4) << 3));
    __syncthreads();

    // ---- QK^T: S[q][kt], 8 key tiles ----
    f32x4 s_acc[8];
    #pragma unroll
    for (int ct = 0; ct < 8; ++ct) {
        s_acc[ct] = (f32x4){0.f, 0.f, 0.f, 0.f};
        int krow = ct * 16 + (lane & 15);
        #pragma unroll
        for (int kk = 0; kk < 2; ++kk) {
            int cb = kk * 64 + ((lane >> 4) << 4);
            short8 kf = *(const short8*)((const char*)sK + krow * 128 + (cb ^ ((krow & 7) << 4)));
            s_acc[ct] = __builtin_amdgcn_mfma_f32_16x16x32_bf16(qf[kk], kf, s_acc[ct], 0, 0, 0);
        }
    }

    // ---- band mask + softmax ----
    const int kcol = lane & 15;
    const int qb = w * 16 + ((lane >> 4) << 2);
    float p[8][4];
    #pragma unroll
    for (int r = 0; r < 4; ++r) {
        int q = qb + r;
        float m = -1e30f;
        #pragma unroll
        for (int ct = 0; ct < 8; ++ct) {
            int kt = ct * 16 + kcol;
            bool valid = (kt > q) && (kt <= q + 64) && (s0 + kt >= 64);
            float sc = valid ? s_acc[ct][r] * 0.125f : -1e30f;
            p[ct][r] = sc;
            m = fmaxf(m, sc);
        }
        #pragma unroll
        for (int off = 1; off < 16; off <<= 1) m = fmaxf(m, __shfl_xor(m, off));
        float sm = 0.f;
        #pragma unroll
        for (int ct = 0; ct < 8; ++ct) {
            float e = __expf(p[ct][r] - m);
            p[ct][r] = e;
            sm += e;
        }
        #pragma unroll
        for (int off = 1; off < 16; off <<= 1) sm += __shfl_xor(sm, off);
        float inv = 1.f / sm;
        #pragma unroll
        for (int ct = 0; ct < 8; ++ct) p[ct][r] *= inv;
    }

    // ---- write P to per-wave swizzled LDS [16][128] ----
    #pragma unroll
    for (int ct = 0; ct < 8; ++ct)
        #pragma unroll
        for (int r = 0; r < 4; ++r) {
            int row = ((lane >> 4) << 2) + r;
            int b = row * 256 + (((ct * 16 + kcol) * 2) ^ ((row & 7) << 4));
            *(short*)((char*)&sP[w][0] + b) = f2b(p[ct][r]);
        }

    // ---- PV: O[q][d] = P(16x128) . V(128x64) ----
    short8 pf[4];
    #pragma unroll
    for (int kk = 0; kk < 4; ++kk) {
        int row = lane & 15;
        int cb = kk * 64 + ((lane >> 4) << 4);
        pf[kk] = *(const short8*)((const char*)&sP[w][0] + row * 256 + (cb ^ ((row & 7) << 4)));
    }
    f32x4 o_acc[4];
    #pragma unroll
    for (int nt = 0; nt < 4; ++nt) {
        o_acc[nt] = (f32x4){0.f, 0.f, 0.f, 0.f};
        #pragma unroll
        for (int kk = 0; kk < 4; ++kk) {
            int vrow = nt * 16 + (lane & 15);
            int cb = kk * 64 + ((lane >> 4) << 4);
            short8 vf = *(const short8*)((const char*)sVt + vrow * 256 + (cb ^ ((vrow & 7) << 4)));
            o_acc[nt] = __builtin_amdgcn_mfma_f32_16x16x32_bf16(pf[kk], vf, o_acc[nt], 0, 0, 0);
        }
    }

    // ---- store O (bf16) ----
    #pragma unroll
    for (int nt = 0; nt < 4; ++nt)
        #pragma unroll
        for (int r = 0; r < 4; ++r) {
            int q = s0 + qb + r;
            int dcol = h * 64 + nt * 16 + (lane & 15);
            O[(size_t)q * HIDDEN + dcol] = f2b(o_acc[nt][r]);
        }
}

// ---------------- launcher ----------------
extern "C" void kernel_launch(void* const* d_in, const int* in_sizes, int n_in,
                              void* d_out, int out_size, void* d_ws, size_t ws_size,
                              hipStream_t stream) {
    const float* X  = (const float*)d_in[0];
    const float* Wq = (const float*)d_in[1];
    const float* Wk = (const float*)d_in[2];
    const float* Wv = (const float*)d_in[3];
    const float* Wo = (const float*)d_in[4];
    float* out = (float*)d_out;

    char* ws = (char*)d_ws;
    short* Xb    = (short*)(ws);                 // 2048*768   bf16
    short* Wqkvb = (short*)(ws + 3145728);       // 2304*768   bf16
    short* Wob   = (short*)(ws + 6684672);       // 768*768    bf16
    short* QKVb  = (short*)(ws + 7864320);       // 2048*2304  bf16
    short* Attnb = (short*)(ws + 17301504);      // 2048*768   bf16

    convert_all<<<1536 + 4 * 576, 256, 0, stream>>>(X, Wq, Wk, Wv, Wo, Xb, Wqkvb, Wob);

    // QKV = X @ [Wq;Wk;Wv]^T : M=2048, N=2304, K=768 -> bf16
    gemm_bt<1><<<(S_LEN / 128) * (QKV_LD / 128), 256, 0, stream>>>(Xb, Wqkvb, QKVb, HIDDEN, QKV_LD / 128, QKV_LD);

    // sliding-window attention (MFMA)
    attn_mfma<<<(S_LEN / 64) * NHEADS, 256, 0, stream>>>(QKVb, Attnb);

    // out = attn @ Wo^T : M=2048, N=768, K=768 -> f32
    gemm_bt<0><<<(S_LEN / 128) * (HIDDEN / 128), 256, 0, stream>>>(Attnb, Wob, out, HIDDEN, HIDDEN / 128, HIDDEN);
}